// Round 3
// 1702.524 us; speedup vs baseline: 1.6277x; 1.6277x over previous
//
#include <hip/hip_runtime.h>

#define N_ROWS 32768

typedef unsigned short u16;
typedef __attribute__((ext_vector_type(8))) short short8;
typedef __attribute__((ext_vector_type(4))) float f32x4;
typedef __attribute__((ext_vector_type(4))) u16 us4;

// ================================================================ threefry
__device__ __forceinline__ unsigned rotl32(unsigned x, unsigned r) {
  return (x << r) | (x >> (32u - r));
}
__device__ __forceinline__ void tf_round(unsigned &x0, unsigned &x1, unsigned r) {
  x0 += x1; x1 = rotl32(x1, r); x1 ^= x0;
}

__global__ void mask_kernel(float* __restrict__ mask) {
  int j = threadIdx.x;
  if (j >= 64) return;
  const unsigned k0 = 0u, k1 = 42u;
  const unsigned k2 = 0x1BD11BDAu ^ k0 ^ k1;
  unsigned x0 = 0u;
  unsigned x1 = (unsigned)j;
  x0 += k0; x1 += k1;
  tf_round(x0, x1, 13); tf_round(x0, x1, 15); tf_round(x0, x1, 26); tf_round(x0, x1, 6);
  x0 += k1; x1 += k2 + 1u;
  tf_round(x0, x1, 17); tf_round(x0, x1, 29); tf_round(x0, x1, 16); tf_round(x0, x1, 24);
  x0 += k2; x1 += k0 + 2u;
  tf_round(x0, x1, 13); tf_round(x0, x1, 15); tf_round(x0, x1, 26); tf_round(x0, x1, 6);
  x0 += k0; x1 += k1 + 3u;
  tf_round(x0, x1, 17); tf_round(x0, x1, 29); tf_round(x0, x1, 16); tf_round(x0, x1, 24);
  x0 += k1; x1 += k2 + 4u;
  tf_round(x0, x1, 13); tf_round(x0, x1, 15); tf_round(x0, x1, 26); tf_round(x0, x1, 6);
  x0 += k2; x1 += k0 + 5u;
  unsigned bits = x0 ^ x1;
  float u = __uint_as_float((bits >> 9) | 0x3f800000u) - 1.0f;
  mask[j] = (u < 0.1f) ? 1.0f : 0.0f;
}

// ------------------------------------------------- numpy-pairwise ||row||^2
__global__ void norme_kernel(const float* __restrict__ cb, float* __restrict__ nE) {
#pragma clang fp contract(off)
  int k = blockIdx.x * blockDim.x + threadIdx.x;  // 0..8191
  const float* r = cb + (size_t)k * 256;
  float halves[2];
#pragma unroll
  for (int h = 0; h < 2; h++) {
    float a[8];
#pragma unroll
    for (int j = 0; j < 8; j++) a[j] = 0.0f;
    for (int t = 0; t < 16; t++) {
      float4 v0 = *(const float4*)&r[h * 128 + 8 * t];
      float4 v1 = *(const float4*)&r[h * 128 + 8 * t + 4];
      a[0] = a[0] + v0.x * v0.x; a[1] = a[1] + v0.y * v0.y;
      a[2] = a[2] + v0.z * v0.z; a[3] = a[3] + v0.w * v0.w;
      a[4] = a[4] + v1.x * v1.x; a[5] = a[5] + v1.y * v1.y;
      a[6] = a[6] + v1.z * v1.z; a[7] = a[7] + v1.w * v1.w;
    }
    halves[h] = ((a[0] + a[1]) + (a[2] + a[3])) + ((a[4] + a[5]) + (a[6] + a[7]));
  }
  nE[k] = halves[0] + halves[1];
}

__global__ void rownorm_kernel(const float* __restrict__ R, float* __restrict__ rr) {
#pragma clang fp contract(off)
  int tid = threadIdx.x;
  int row = blockIdx.x * 64 + (tid >> 2);
  int q = tid & 3;
  int h = q >> 1;
  int j0 = (q & 1) << 2;
  const float* p = R + (size_t)row * 256 + h * 128 + j0;
  float a[4] = {0.f, 0.f, 0.f, 0.f};
  for (int t = 0; t < 16; t++) {
    float4 v = *(const float4*)&p[8 * t];
    a[0] = a[0] + v.x * v.x; a[1] = a[1] + v.y * v.y;
    a[2] = a[2] + v.z * v.z; a[3] = a[3] + v.w * v.w;
  }
  float s = (a[0] + a[1]) + (a[2] + a[3]);
  float half = s + __shfl_xor(s, 1, 4);
  float tot = half + __shfl_xor(half, 2, 4);
  if (q == 0) rr[row] = tot;
}

// ---------------------------------------------------------------- bf16 split helpers
__device__ __forceinline__ u16 f2bf(float x) {
  unsigned u = __float_as_uint(x);
  unsigned r = u + 0x7fffu + ((u >> 16) & 1u);
  return (u16)(r >> 16);
}
__device__ __forceinline__ float bf2f(u16 h) {
  return __uint_as_float(((unsigned)h) << 16);
}

// fp32 [rows][256]  ->  interleaved [row][ hi(256 bf16) | lo(256 bf16) ]
// grid * 256 threads == rows * 32 exactly
__global__ void cvt_kernel(const float* __restrict__ in, u16* __restrict__ out) {
  int gid = blockIdx.x * 256 + threadIdx.x;
  int row = gid >> 5, seg = gid & 31;
  const float* p = in + (size_t)row * 256 + seg * 8;
  u16* H = out + (size_t)row * 512 + seg * 8;
  float4 a = *(const float4*)p;
  float4 b = *(const float4*)(p + 4);
  float v[8] = {a.x, a.y, a.z, a.w, b.x, b.y, b.z, b.w};
  u16 hh[8], ll[8];
#pragma unroll
  for (int t = 0; t < 8; t++) {
    hh[t] = f2bf(v[t]);
    ll[t] = f2bf(v[t] - bf2f(hh[t]));
  }
  us4 H0 = {hh[0], hh[1], hh[2], hh[3]};
  us4 H1 = {hh[4], hh[5], hh[6], hh[7]};
  us4 L0 = {ll[0], ll[1], ll[2], ll[3]};
  us4 L1 = {ll[4], ll[5], ll[6], ll[7]};
  *(us4*)&H[0] = H0;  *(us4*)&H[4] = H1;
  *(us4*)&H[256] = L0; *(us4*)&H[260] = L1;
}

// ---------------------------------------------------------------- BN prep
__global__ void bnprep_kernel(const double* __restrict__ psum, const double* __restrict__ psq,
                              const float* __restrict__ g, const float* __restrict__ bt,
                              float* __restrict__ a, float* __restrict__ c, int F) {
  int f = blockIdx.x * blockDim.x + threadIdx.x;
  if (f >= F) return;
  double s = 0.0, q = 0.0;
  const double* ps = psum + (size_t)f * 512;
  const double* pq = psq + (size_t)f * 512;
  for (int b = 0; b < 512; b++) { s += ps[b]; q += pq[b]; }
  double mu  = s * (1.0 / 32768.0);
  double var = q * (1.0 / 32768.0) - mu * mu;
  double inv = (double)g[f] / sqrt(var + 1e-5);
  a[f] = (float)inv;
  c[f] = (float)((double)bt[f] - mu * inv);
}

// ---------------------------------------------------------------- GEMM (enc/dec)
template <int MODE, int STATS>
__global__ __launch_bounds__(256)
void gemm64(const float* __restrict__ A, const float* __restrict__ W,
            const float* __restrict__ bias, const float* __restrict__ p0,
            const float* __restrict__ p1, const float* __restrict__ A3,
            float* __restrict__ out,
            double* __restrict__ psum, double* __restrict__ psq, int K, int F) {
  __shared__ float As[16][68];
  __shared__ float Bs[16][68];
  __shared__ double psumS[4][64];
  __shared__ double psqS[4][64];
  const int tid = threadIdx.x;
  const int row0 = blockIdx.y << 6;
  const int col0 = blockIdx.x << 6;
  const int ty = tid >> 4, tx = tid & 15;
  const int ar = tid >> 2, aq = (tid & 3) << 2;
  const int bk = tid >> 4, bc = (tid & 15) << 2;
  float acc[4][4] = {};
  for (int k0 = 0; k0 < K; k0 += 16) {
    const size_t aoff = (size_t)(row0 + ar) * K + k0 + aq;
    float4 av = *(const float4*)&A[aoff];
    float4 bv = *(const float4*)&W[(size_t)(k0 + bk) * F + col0 + bc];
    float a4[4] = { av.x, av.y, av.z, av.w };
    if (MODE == 0) {
#pragma unroll
      for (int j = 0; j < 4; j++) {
        int gk = k0 + aq + j;
        float m = p0[gk];
        float v = (m != 0.0f || (row0 + ar) == 0) ? 0.0f : a4[j];
        a4[j] = v + p1[gk];
      }
    } else if (MODE == 1) {
#pragma unroll
      for (int j = 0; j < 4; j++) {
        int gk = k0 + aq + j;
        a4[j] = fmaxf(fmaf(a4[j], p0[gk], p1[gk]), 0.0f);
      }
    } else if (MODE == 3) {
      float4 v1 = *(const float4*)&p0[aoff];
      float4 v2 = *(const float4*)&p1[aoff];
      float4 v3 = *(const float4*)&A3[aoff];
      a4[0] = ((a4[0] + v1.x) + v2.x) + v3.x;
      a4[1] = ((a4[1] + v1.y) + v2.y) + v3.y;
      a4[2] = ((a4[2] + v1.z) + v2.z) + v3.z;
      a4[3] = ((a4[3] + v1.w) + v2.w) + v3.w;
    }
    __syncthreads();
#pragma unroll
    for (int j = 0; j < 4; j++) As[aq + j][ar] = a4[j];
    *(float4*)&Bs[bk][bc] = bv;
    __syncthreads();
#pragma unroll
    for (int kc = 0; kc < 16; kc++) {
      float4 a = *(const float4*)&As[kc][ty << 2];
      float4 b = *(const float4*)&Bs[kc][tx << 2];
      float a_[4] = { a.x, a.y, a.z, a.w };
      float b_[4] = { b.x, b.y, b.z, b.w };
#pragma unroll
      for (int i = 0; i < 4; i++)
#pragma unroll
        for (int j = 0; j < 4; j++)
          acc[i][j] = fmaf(a_[i], b_[j], acc[i][j]);
    }
  }
  float bj[4];
#pragma unroll
  for (int j = 0; j < 4; j++) bj[j] = bias[col0 + (tx << 2) + j];
  double sj[4] = {}, qj[4] = {};
#pragma unroll
  for (int i = 0; i < 4; i++) {
    float v[4];
#pragma unroll
    for (int j = 0; j < 4; j++) {
      v[j] = acc[i][j] + bj[j];
      if (STATS) {
        sj[j] += (double)v[j];
        qj[j] += (double)v[j] * (double)v[j];
      }
    }
    float4 vv = { v[0], v[1], v[2], v[3] };
    *(float4*)&out[(size_t)(row0 + (ty << 2) + i) * F + col0 + (tx << 2)] = vv;
  }
  if (STATS) {
#pragma unroll
    for (int j = 0; j < 4; j++) {
      sj[j] += __shfl_down(sj[j], 32);
      sj[j] += __shfl_down(sj[j], 16);
      qj[j] += __shfl_down(qj[j], 32);
      qj[j] += __shfl_down(qj[j], 16);
    }
    const int w = tid >> 6;
    if ((tid & 63) < 16) {
#pragma unroll
      for (int j = 0; j < 4; j++) {
        psumS[w][((tid & 15) << 2) + j] = sj[j];
        psqS[w][((tid & 15) << 2) + j] = qj[j];
      }
    }
    __syncthreads();
    if (tid < 64) {
      double ds = (psumS[0][tid] + psumS[1][tid]) + (psumS[2][tid] + psumS[3][tid]);
      double dq = (psqS[0][tid] + psqS[1][tid]) + (psqS[2][tid] + psqS[3][tid]);
      psum[(size_t)(col0 + tid) * 512 + blockIdx.y] = ds;
      psq[(size_t)(col0 + tid) * 512 + blockIdx.y] = dq;
    }
  }
}

// ---------------------------------------------------------------- async global->LDS
__device__ __forceinline__ void gld16(const void* gp, void* lp) {
  __builtin_amdgcn_global_load_lds(
      (__attribute__((address_space(1))) unsigned int*)gp,
      (__attribute__((address_space(3))) unsigned int*)lp,
      16, 0, 0);
}

#define MFMA16(a, b, c) __builtin_amdgcn_mfma_f32_16x16x32_bf16(a, b, c, 0, 0, 0)

// ---------------------------------------------------------------- quantize (bf16x3 MFMA + fp32 rescore)
// Block: 64 rows x all 2048 codes (chunks of 128). 256 threads = 4 waves (2x2).
// Pass 1 (approx): acc = Rhi*Ehi + Rhi*Elo + Rlo*Ehi via mfma_f32_16x16x32_bf16;
//   track per-row TOP-2 candidate codes (approx error ~6e-9 << candidate margin).
// Pass 2 (exact): fp32 dot for the 2 candidates, d = (rr - 2P) + nE, pick min
//   (first-index tie-break) -> same numeric class as the passing fp32 kernel.
// LDS: dest linear (global_load_lds), global source k-chunk pre-swizzled with
// chunk ^= (row>>1)&3; fragment reads apply the same XOR -> 2-way (free) banks.
__global__ __launch_bounds__(256, 2)
void quantize_mfma(const float* __restrict__ Rf, u16* Rcvt,
                   const float* __restrict__ Ef, const u16* __restrict__ Ecvt,
                   const float* __restrict__ nEp, const float* __restrict__ rr,
                   float* __restrict__ ce, float* __restrict__ resn) {
  __shared__ __align__(16) u16 As[2][64][32];    // [hi/lo][row][k]   8 KB
  __shared__ __align__(16) u16 Bs[2][128][32];   // [hi/lo][code][k] 16 KB
  __shared__ float sD1[2][64], sD2[2][64];
  __shared__ int sI1[2][64], sI2[2][64];
  __shared__ int s_iA[64], s_iB[64];

  const int tid = threadIdx.x;
  const int row0 = blockIdx.x << 6;
  const int w = tid >> 6;          // wave 0..3
  const int lane = tid & 63;
  const int wr = w >> 1, wc = w & 1;
  const int l15 = lane & 15, l4 = lane >> 4;

  // per-lane rows: row0 + 32*wr + 16*i + 4*l4 + r   (s = i*4 + r)
  float rrv[8];
#pragma unroll
  for (int s = 0; s < 8; s++)
    rrv[s] = rr[row0 + 32 * wr + 16 * (s >> 2) + 4 * l4 + (s & 3)];

  float bd1[8], bd2[8];
  int bi1[8], bi2[8];
#pragma unroll
  for (int s = 0; s < 8; s++) { bd1[s] = 3.0e38f; bd2[s] = 3.0e38f; bi1[s] = 0; bi2[s] = 1; }

  // staging lane geometry: LDS dest linear (base + lane*16B); global source
  // k-chunk pre-swizzled so reads with the same XOR land conflict-free.
  const int str = lane >> 2;                                   // row within 16-row stripe
  const int sdst = (lane & 3) << 3;                            // linear LDS chunk (u16)
  const int ssrc = (((lane & 3) ^ ((lane >> 3) & 3)) << 3);    // swizzled source chunk (u16)
  const int krd = ((l15 >> 1) & 3) << 3;                       // read-side XOR key (u16)

  for (int n0 = 0; n0 < 2048; n0 += 128) {
    f32x4 acc[2][4] = {};
    for (int k0 = 0; k0 < 256; k0 += 32) {
      __syncthreads();
      {
        const u16* gA = Rcvt + (size_t)(row0 + 16 * w + str) * 512 + k0 + ssrc;
        gld16(gA,       &As[0][16 * w + str][sdst]);
        gld16(gA + 256, &As[1][16 * w + str][sdst]);
#pragma unroll
        for (int q = 0; q < 2; q++) {
          const int rb = 32 * w + 16 * q + str;
          const u16* gB = Ecvt + (size_t)(n0 + rb) * 512 + k0 + ssrc;
          gld16(gB,       &Bs[0][rb][sdst]);
          gld16(gB + 256, &Bs[1][rb][sdst]);
        }
      }
      __syncthreads();
      short8 ah[2], al[2], bh[4], bl[4];
#pragma unroll
      for (int i = 0; i < 2; i++) {
        const int ro = 32 * wr + 16 * i + l15;
        ah[i] = *(const short8*)&As[0][ro][(l4 << 3) ^ krd];
        al[i] = *(const short8*)&As[1][ro][(l4 << 3) ^ krd];
      }
#pragma unroll
      for (int j = 0; j < 4; j++) {
        const int ro = 64 * wc + 16 * j + l15;
        bh[j] = *(const short8*)&Bs[0][ro][(l4 << 3) ^ krd];
        bl[j] = *(const short8*)&Bs[1][ro][(l4 << 3) ^ krd];
      }
#pragma unroll
      for (int i = 0; i < 2; i++)
#pragma unroll
        for (int j = 0; j < 4; j++) {
          acc[i][j] = MFMA16(ah[i], bh[j], acc[i][j]);
          acc[i][j] = MFMA16(ah[i], bl[j], acc[i][j]);
          acc[i][j] = MFMA16(al[i], bh[j], acc[i][j]);
        }
    }
    // top-2 update: cols ascend with j and n0 -> strict < keeps first min
#pragma unroll
    for (int j = 0; j < 4; j++) {
      const int col = n0 + 64 * wc + 16 * j + l15;
      const float nn = nEp[col];
#pragma unroll
      for (int i = 0; i < 2; i++)
#pragma unroll
        for (int r = 0; r < 4; r++) {
          const int s = i * 4 + r;
          float t = rrv[s] - 2.0f * acc[i][j][r];
          float d = t + nn;
          if (d < bd2[s]) {
            if (d < bd1[s]) {
              bd2[s] = bd1[s]; bi2[s] = bi1[s];
              bd1[s] = d; bi1[s] = col;
            } else {
              bd2[s] = d; bi2[s] = col;
            }
          }
        }
    }
  }

  // merge top-2 pairs over the 16 lanes holding the same row (l15 dimension)
#pragma unroll
  for (int s = 0; s < 8; s++) {
    float d1 = bd1[s], d2 = bd2[s];
    int i1 = bi1[s], i2 = bi2[s];
#pragma unroll
    for (int off = 1; off <= 8; off <<= 1) {
      float e1 = __shfl_xor(d1, off, 16);
      float e2 = __shfl_xor(d2, off, 16);
      int j1 = __shfl_xor(i1, off, 16);
      int j2 = __shfl_xor(i2, off, 16);
      if (e1 < d1 || (e1 == d1 && j1 < i1)) {
        bool ps = (d1 < e2) || (d1 == e2 && i1 < j2);
        d2 = ps ? d1 : e2; i2 = ps ? i1 : j2;
        d1 = e1; i1 = j1;
      } else {
        bool ps = (e1 < d2) || (e1 == d2 && j1 < i2);
        if (ps) { d2 = e1; i2 = j1; }
      }
    }
    if (l15 == 0) {
      int lr = 32 * wr + 16 * (s >> 2) + 4 * l4 + (s & 3);
      sD1[wc][lr] = d1; sI1[wc][lr] = i1;
      sD2[wc][lr] = d2; sI2[wc][lr] = i2;
    }
  }
  __syncthreads();
  if (tid < 64) {
    float d1 = sD1[0][tid], d2 = sD2[0][tid];
    int i1 = sI1[0][tid], i2 = sI2[0][tid];
    float e1 = sD1[1][tid], e2 = sD2[1][tid];
    int j1 = sI1[1][tid], j2 = sI2[1][tid];
    int iA, iB;
    if (e1 < d1 || (e1 == d1 && j1 < i1)) {
      iA = j1;
      bool ps = (d1 < e2) || (d1 == e2 && i1 < j2);
      iB = ps ? i1 : j2;
    } else {
      iA = i1;
      bool ps = (e1 < d2) || (e1 == d2 && j1 < i2);
      iB = ps ? j1 : i2;
    }
    s_iA[tid] = iA; s_iB[tid] = iB;
  }
  __syncthreads();

  // fp32 rescore of the 2 candidates (4 threads per row), then gather +
  // residual + next-stage hi/lo conversion (in place, own rows only)
  const int orow = tid >> 2;
  const int q = tid & 3;
  const int gr = row0 + orow;
  const int iA = s_iA[orow], iB = s_iB[orow];
  const float* __restrict__ Rr = Rf + (size_t)gr * 256;
  const float* __restrict__ EA = Ef + (size_t)iA * 256;
  const float* __restrict__ EB = Ef + (size_t)iB * 256;
  float pa[4] = {0.f, 0.f, 0.f, 0.f}, pb[4] = {0.f, 0.f, 0.f, 0.f};
  const int c0 = q << 6;
  for (int t = 0; t < 16; t++) {
    float4 rv = *(const float4*)&Rr[c0 + 4 * t];
    float4 ea = *(const float4*)&EA[c0 + 4 * t];
    float4 eb = *(const float4*)&EB[c0 + 4 * t];
    pa[0] = fmaf(rv.x, ea.x, pa[0]); pa[1] = fmaf(rv.y, ea.y, pa[1]);
    pa[2] = fmaf(rv.z, ea.z, pa[2]); pa[3] = fmaf(rv.w, ea.w, pa[3]);
    pb[0] = fmaf(rv.x, eb.x, pb[0]); pb[1] = fmaf(rv.y, eb.y, pb[1]);
    pb[2] = fmaf(rv.z, eb.z, pb[2]); pb[3] = fmaf(rv.w, eb.w, pb[3]);
  }
  float sA = (pa[0] + pa[1]) + (pa[2] + pa[3]);
  float sB = (pb[0] + pb[1]) + (pb[2] + pb[3]);
  sA += __shfl_xor(sA, 1, 4); sA += __shfl_xor(sA, 2, 4);
  sB += __shfl_xor(sB, 1, 4); sB += __shfl_xor(sB, 2, 4);
  const float rrow = rr[gr];
  float dA = (rrow - 2.0f * sA) + nEp[iA];
  float dB = (rrow - 2.0f * sB) + nEp[iB];
  const int idx = (dB < dA || (dB == dA && iB < iA)) ? iB : iA;

  const int oc0 = q << 6;
  const float* __restrict__ Er = Ef + (size_t)idx * 256;
  float* __restrict__ Cr = ce + (size_t)gr * 256;
  if (resn) {
    float* __restrict__ Nr = resn + (size_t)gr * 256;
    u16* Hr = Rcvt + (size_t)gr * 512;
    for (int c = oc0; c < oc0 + 64; c += 4) {
      float4 e = *(const float4*)&Er[c];
      float4 r = *(const float4*)&Rr[c];
      *(float4*)&Cr[c] = e;
      float4 dd = { r.x - e.x, r.y - e.y, r.z - e.z, r.w - e.w };
      *(float4*)&Nr[c] = dd;
      u16 h0 = f2bf(dd.x), h1 = f2bf(dd.y), h2 = f2bf(dd.z), h3 = f2bf(dd.w);
      us4 hv = { h0, h1, h2, h3 };
      us4 lv = { f2bf(dd.x - bf2f(h0)), f2bf(dd.y - bf2f(h1)),
                 f2bf(dd.z - bf2f(h2)), f2bf(dd.w - bf2f(h3)) };
      *(us4*)&Hr[c] = hv;
      *(us4*)&Hr[256 + c] = lv;
    }
  } else {
    for (int c = oc0; c < oc0 + 64; c += 4) {
      float4 e = *(const float4*)&Er[c];
      *(float4*)&Cr[c] = e;
    }
  }
}

// ---------------------------------------------------------------- launch
extern "C" void kernel_launch(void* const* d_in, const int* in_sizes, int n_in,
                              void* d_out, int out_size, void* d_ws, size_t ws_size,
                              hipStream_t stream) {
  (void)in_sizes; (void)n_in; (void)out_size; (void)ws_size;
  const float* x     = (const float*)d_in[0];
  const float* pos   = (const float*)d_in[1];
  const float* e_w0  = (const float*)d_in[2];
  const float* e_b0  = (const float*)d_in[3];
  const float* e_g0  = (const float*)d_in[4];
  const float* e_bt0 = (const float*)d_in[5];
  const float* e_w1  = (const float*)d_in[6];
  const float* e_b1  = (const float*)d_in[7];
  const float* e_g1  = (const float*)d_in[8];
  const float* e_bt1 = (const float*)d_in[9];
  const float* e_w2  = (const float*)d_in[10];
  const float* e_b2  = (const float*)d_in[11];
  const float* cb    = (const float*)d_in[12];
  const float* d_w0  = (const float*)d_in[13];
  const float* d_b0  = (const float*)d_in[14];
  const float* d_g0  = (const float*)d_in[15];
  const float* d_bt0 = (const float*)d_in[16];
  const float* d_w1  = (const float*)d_in[17];
  const float* d_b1  = (const float*)d_in[18];
  const float* d_g1  = (const float*)d_in[19];
  const float* d_bt1 = (const float*)d_in[20];
  const float* d_w2  = (const float*)d_in[21];
  const float* d_b2  = (const float*)d_in[22];

  // ---------------- workspace layout (float offsets) ----------
  float* ws = (float*)d_ws;
  float* mask   = ws + 64;                         // 64
  float* aff    = ws + 128;                        // 1536
  float* nE     = ws + 1664;                       // 8192
  double* psum  = (double*)(ws + 16384);           // 131072 dbl
  double* psq   = (double*)(ws + 278528);          // 131072 dbl
  float* g1     = ws + 540672;                     // dec h1' [N,256]
  float* g0     = g1 + (size_t)N_ROWS * 256;       // dec h0' [N,128]
  float* rr     = g0 + (size_t)N_ROWS * 128;       // N

  float* e0a = aff + 0;    float* e0c = aff + 128;
  float* e1a = aff + 256;  float* e1c = aff + 512;
  float* d0a = aff + 768;  float* d0c = aff + 1024;
  float* d1a = aff + 1280; float* d1c = aff + 1408;

  // ---------------- output layout ----------------
  float* outp = (float*)d_out;
  float* xhat = outp;
  float* res0 = outp + (size_t)N_ROWS * 64;
  float* res1 = res0 + (size_t)N_ROWS * 256;
  float* res2 = res1 + (size_t)N_ROWS * 256;
  float* res3 = res2 + (size_t)N_ROWS * 256;
  float* ce0  = res0 + (size_t)4 * N_ROWS * 256;
  float* ce1  = ce0 + (size_t)N_ROWS * 256;
  float* ce2  = ce1 + (size_t)N_ROWS * 256;
  float* ce3  = ce2 + (size_t)N_ROWS * 256;

  // scratch overlays into not-yet-written output regions (lifetime-checked):
  float* h0 = ce2;   // enc h0 [N,128]; ce2 written at quantize stage 2
  float* h1 = ce3;   // enc h1 [N,256]; ce3 written at quantize stage 3
  // bf16 hi/lo overlays:
  //  - Ecvt (8192x512 u16 = 8.0 MB) sits in xhat (8.0 MB), free until final gemm
  //  - Rcvt (32768x512 u16 = 32 MB) sits in ce3 (exact size); each quantize block
  //    reads only its own 64 rows and rewrites them after its last read; stage 3
  //    overwrites the region with ce3 fp32 in its epilogue.
  u16* Ecvt = (u16*)xhat;
  u16* Rcvt = (u16*)ce3;

  mask_kernel<<<1, 64, 0, stream>>>(mask);
  norme_kernel<<<32, 256, 0, stream>>>(cb, nE);
  cvt_kernel<<<1024, 256, 0, stream>>>(cb, Ecvt);           // 8192 codebook rows

  // encoder
  gemm64<0, 1><<<dim3(2, 512), 256, 0, stream>>>(x, e_w0, e_b0, mask, pos, nullptr,
                                                 h0, psum, psq, 64, 128);
  bnprep_kernel<<<1, 256, 0, stream>>>(psum, psq, e_g0, e_bt0, e0a, e0c, 128);
  gemm64<1, 1><<<dim3(4, 512), 256, 0, stream>>>(h0, e_w1, e_b1, e0a, e0c, nullptr,
                                                 h1, psum, psq, 128, 256);
  bnprep_kernel<<<1, 256, 0, stream>>>(psum, psq, e_g1, e_bt1, e1a, e1c, 256);
  gemm64<1, 0><<<dim3(4, 512), 256, 0, stream>>>(h1, e_w2, e_b2, e1a, e1c, nullptr,
                                                 res0, nullptr, nullptr, 256, 256);

  // residual VQ (bf16x3 MFMA distance GEMM + fp32 rescore)
  cvt_kernel<<<4096, 256, 0, stream>>>(res0, Rcvt);         // 32768 rows
  rownorm_kernel<<<512, 256, 0, stream>>>(res0, rr);
  quantize_mfma<<<512, 256, 0, stream>>>(res0, Rcvt,
                                         cb + (size_t)0 * 2048 * 256,
                                         Ecvt + (size_t)0 * 2048 * 512,
                                         nE + 0, rr, ce0, res1);
  rownorm_kernel<<<512, 256, 0, stream>>>(res1, rr);
  quantize_mfma<<<512, 256, 0, stream>>>(res1, Rcvt,
                                         cb + (size_t)1 * 2048 * 256,
                                         Ecvt + (size_t)1 * 2048 * 512,
                                         nE + 2048, rr, ce1, res2);
  rownorm_kernel<<<512, 256, 0, stream>>>(res2, rr);
  quantize_mfma<<<512, 256, 0, stream>>>(res2, Rcvt,
                                         cb + (size_t)2 * 2048 * 256,
                                         Ecvt + (size_t)2 * 2048 * 512,
                                         nE + 4096, rr, ce2, res3);
  rownorm_kernel<<<512, 256, 0, stream>>>(res3, rr);
  quantize_mfma<<<512, 256, 0, stream>>>(res3, Rcvt,
                                         cb + (size_t)3 * 2048 * 256,
                                         Ecvt + (size_t)3 * 2048 * 512,
                                         nE + 6144, rr, ce3, nullptr);

  // decoder (L0 fuses zq = ((ce0+ce1)+ce2)+ce3 in the A prologue)
  gemm64<3, 1><<<dim3(4, 512), 256, 0, stream>>>(ce0, d_w0, d_b0, ce1, ce2, ce3,
                                                 g1, psum, psq, 256, 256);
  bnprep_kernel<<<1, 256, 0, stream>>>(psum, psq, d_g0, d_bt0, d0a, d0c, 256);
  gemm64<1, 1><<<dim3(2, 512), 256, 0, stream>>>(g1, d_w1, d_b1, d0a, d0c, nullptr,
                                                 g0, psum, psq, 256, 128);
  bnprep_kernel<<<1, 256, 0, stream>>>(psum, psq, d_g1, d_bt1, d1a, d1c, 128);
  gemm64<1, 0><<<dim3(1, 512), 256, 0, stream>>>(g0, d_w2, d_b2, d1a, d1c, nullptr,
                                                 xhat, nullptr, nullptr, 128, 64);
}

// Round 6
// 1650.310 us; speedup vs baseline: 1.6792x; 1.0316x over previous
//
#include <hip/hip_runtime.h>

#define N_ROWS 32768

typedef unsigned short u16;
typedef __attribute__((ext_vector_type(8))) short short8;
typedef __attribute__((ext_vector_type(4))) float f32x4;
typedef __attribute__((ext_vector_type(4))) u16 us4;

// ================================================================ threefry
__device__ __forceinline__ unsigned rotl32(unsigned x, unsigned r) {
  return (x << r) | (x >> (32u - r));
}
__device__ __forceinline__ void tf_round(unsigned &x0, unsigned &x1, unsigned r) {
  x0 += x1; x1 = rotl32(x1, r); x1 ^= x0;
}

__global__ void mask_kernel(float* __restrict__ mask) {
  int j = threadIdx.x;
  if (j >= 64) return;
  const unsigned k0 = 0u, k1 = 42u;
  const unsigned k2 = 0x1BD11BDAu ^ k0 ^ k1;
  unsigned x0 = 0u;
  unsigned x1 = (unsigned)j;
  x0 += k0; x1 += k1;
  tf_round(x0, x1, 13); tf_round(x0, x1, 15); tf_round(x0, x1, 26); tf_round(x0, x1, 6);
  x0 += k1; x1 += k2 + 1u;
  tf_round(x0, x1, 17); tf_round(x0, x1, 29); tf_round(x0, x1, 16); tf_round(x0, x1, 24);
  x0 += k2; x1 += k0 + 2u;
  tf_round(x0, x1, 13); tf_round(x0, x1, 15); tf_round(x0, x1, 26); tf_round(x0, x1, 6);
  x0 += k0; x1 += k1 + 3u;
  tf_round(x0, x1, 17); tf_round(x0, x1, 29); tf_round(x0, x1, 16); tf_round(x0, x1, 24);
  x0 += k1; x1 += k2 + 4u;
  tf_round(x0, x1, 13); tf_round(x0, x1, 15); tf_round(x0, x1, 26); tf_round(x0, x1, 6);
  x0 += k2; x1 += k0 + 5u;
  unsigned bits = x0 ^ x1;
  float u = __uint_as_float((bits >> 9) | 0x3f800000u) - 1.0f;
  mask[j] = (u < 0.1f) ? 1.0f : 0.0f;
}

// ------------------------------------------------- numpy-pairwise ||row||^2
__global__ void norme_kernel(const float* __restrict__ cb, float* __restrict__ nE) {
#pragma clang fp contract(off)
  int k = blockIdx.x * blockDim.x + threadIdx.x;  // 0..8191
  const float* r = cb + (size_t)k * 256;
  float halves[2];
#pragma unroll
  for (int h = 0; h < 2; h++) {
    float a[8];
#pragma unroll
    for (int j = 0; j < 8; j++) a[j] = 0.0f;
    for (int t = 0; t < 16; t++) {
      float4 v0 = *(const float4*)&r[h * 128 + 8 * t];
      float4 v1 = *(const float4*)&r[h * 128 + 8 * t + 4];
      a[0] = a[0] + v0.x * v0.x; a[1] = a[1] + v0.y * v0.y;
      a[2] = a[2] + v0.z * v0.z; a[3] = a[3] + v0.w * v0.w;
      a[4] = a[4] + v1.x * v1.x; a[5] = a[5] + v1.y * v1.y;
      a[6] = a[6] + v1.z * v1.z; a[7] = a[7] + v1.w * v1.w;
    }
    halves[h] = ((a[0] + a[1]) + (a[2] + a[3])) + ((a[4] + a[5]) + (a[6] + a[7]));
  }
  nE[k] = halves[0] + halves[1];
}

__global__ void rownorm_kernel(const float* __restrict__ R, float* __restrict__ rr) {
#pragma clang fp contract(off)
  int tid = threadIdx.x;
  int row = blockIdx.x * 64 + (tid >> 2);
  int q = tid & 3;
  int h = q >> 1;
  int j0 = (q & 1) << 2;
  const float* p = R + (size_t)row * 256 + h * 128 + j0;
  float a[4] = {0.f, 0.f, 0.f, 0.f};
  for (int t = 0; t < 16; t++) {
    float4 v = *(const float4*)&p[8 * t];
    a[0] = a[0] + v.x * v.x; a[1] = a[1] + v.y * v.y;
    a[2] = a[2] + v.z * v.z; a[3] = a[3] + v.w * v.w;
  }
  float s = (a[0] + a[1]) + (a[2] + a[3]);
  float half = s + __shfl_xor(s, 1, 4);
  float tot = half + __shfl_xor(half, 2, 4);
  if (q == 0) rr[row] = tot;
}

// ---------------------------------------------------------------- bf16 split helpers
__device__ __forceinline__ u16 f2bf(float x) {
  unsigned u = __float_as_uint(x);
  unsigned r = u + 0x7fffu + ((u >> 16) & 1u);
  return (u16)(r >> 16);
}
__device__ __forceinline__ float bf2f(u16 h) {
  return __uint_as_float(((unsigned)h) << 16);
}

// fp32 [rows][256]  ->  interleaved [row][ hi(256 bf16) | lo(256 bf16) ]
// grid * 256 threads == rows * 32 exactly
__global__ void cvt_kernel(const float* __restrict__ in, u16* __restrict__ out) {
  int gid = blockIdx.x * 256 + threadIdx.x;
  int row = gid >> 5, seg = gid & 31;
  const float* p = in + (size_t)row * 256 + seg * 8;
  u16* H = out + (size_t)row * 512 + seg * 8;
  float4 a = *(const float4*)p;
  float4 b = *(const float4*)(p + 4);
  float v[8] = {a.x, a.y, a.z, a.w, b.x, b.y, b.z, b.w};
  u16 hh[8], ll[8];
#pragma unroll
  for (int t = 0; t < 8; t++) {
    hh[t] = f2bf(v[t]);
    ll[t] = f2bf(v[t] - bf2f(hh[t]));
  }
  us4 H0 = {hh[0], hh[1], hh[2], hh[3]};
  us4 H1 = {hh[4], hh[5], hh[6], hh[7]};
  us4 L0 = {ll[0], ll[1], ll[2], ll[3]};
  us4 L1 = {ll[4], ll[5], ll[6], ll[7]};
  *(us4*)&H[0] = H0;  *(us4*)&H[4] = H1;
  *(us4*)&H[256] = L0; *(us4*)&H[260] = L1;
}

// ---------------------------------------------------------------- BN prep
__global__ void bnprep_kernel(const double* __restrict__ psum, const double* __restrict__ psq,
                              const float* __restrict__ g, const float* __restrict__ bt,
                              float* __restrict__ a, float* __restrict__ c, int F) {
  int f = blockIdx.x * blockDim.x + threadIdx.x;
  if (f >= F) return;
  double s = 0.0, q = 0.0;
  const double* ps = psum + (size_t)f * 512;
  const double* pq = psq + (size_t)f * 512;
  for (int b = 0; b < 512; b++) { s += ps[b]; q += pq[b]; }
  double mu  = s * (1.0 / 32768.0);
  double var = q * (1.0 / 32768.0) - mu * mu;
  double inv = (double)g[f] / sqrt(var + 1e-5);
  a[f] = (float)inv;
  c[f] = (float)((double)bt[f] - mu * inv);
}

// ---------------------------------------------------------------- GEMM (enc/dec)
template <int MODE, int STATS>
__global__ __launch_bounds__(256)
void gemm64(const float* __restrict__ A, const float* __restrict__ W,
            const float* __restrict__ bias, const float* __restrict__ p0,
            const float* __restrict__ p1, const float* __restrict__ A3,
            float* __restrict__ out,
            double* __restrict__ psum, double* __restrict__ psq, int K, int F) {
  __shared__ float As[16][68];
  __shared__ float Bs[16][68];
  __shared__ double psumS[4][64];
  __shared__ double psqS[4][64];
  const int tid = threadIdx.x;
  const int row0 = blockIdx.y << 6;
  const int col0 = blockIdx.x << 6;
  const int ty = tid >> 4, tx = tid & 15;
  const int ar = tid >> 2, aq = (tid & 3) << 2;
  const int bk = tid >> 4, bc = (tid & 15) << 2;
  float acc[4][4] = {};
  for (int k0 = 0; k0 < K; k0 += 16) {
    const size_t aoff = (size_t)(row0 + ar) * K + k0 + aq;
    float4 av = *(const float4*)&A[aoff];
    float4 bv = *(const float4*)&W[(size_t)(k0 + bk) * F + col0 + bc];
    float a4[4] = { av.x, av.y, av.z, av.w };
    if (MODE == 0) {
#pragma unroll
      for (int j = 0; j < 4; j++) {
        int gk = k0 + aq + j;
        float m = p0[gk];
        float v = (m != 0.0f || (row0 + ar) == 0) ? 0.0f : a4[j];
        a4[j] = v + p1[gk];
      }
    } else if (MODE == 1) {
#pragma unroll
      for (int j = 0; j < 4; j++) {
        int gk = k0 + aq + j;
        a4[j] = fmaxf(fmaf(a4[j], p0[gk], p1[gk]), 0.0f);
      }
    } else if (MODE == 3) {
      float4 v1 = *(const float4*)&p0[aoff];
      float4 v2 = *(const float4*)&p1[aoff];
      float4 v3 = *(const float4*)&A3[aoff];
      a4[0] = ((a4[0] + v1.x) + v2.x) + v3.x;
      a4[1] = ((a4[1] + v1.y) + v2.y) + v3.y;
      a4[2] = ((a4[2] + v1.z) + v2.z) + v3.z;
      a4[3] = ((a4[3] + v1.w) + v2.w) + v3.w;
    }
    __syncthreads();
#pragma unroll
    for (int j = 0; j < 4; j++) As[aq + j][ar] = a4[j];
    *(float4*)&Bs[bk][bc] = bv;
    __syncthreads();
#pragma unroll
    for (int kc = 0; kc < 16; kc++) {
      float4 a = *(const float4*)&As[kc][ty << 2];
      float4 b = *(const float4*)&Bs[kc][tx << 2];
      float a_[4] = { a.x, a.y, a.z, a.w };
      float b_[4] = { b.x, b.y, b.z, b.w };
#pragma unroll
      for (int i = 0; i < 4; i++)
#pragma unroll
        for (int j = 0; j < 4; j++)
          acc[i][j] = fmaf(a_[i], b_[j], acc[i][j]);
    }
  }
  float bj[4];
#pragma unroll
  for (int j = 0; j < 4; j++) bj[j] = bias[col0 + (tx << 2) + j];
  double sj[4] = {}, qj[4] = {};
#pragma unroll
  for (int i = 0; i < 4; i++) {
    float v[4];
#pragma unroll
    for (int j = 0; j < 4; j++) {
      v[j] = acc[i][j] + bj[j];
      if (STATS) {
        sj[j] += (double)v[j];
        qj[j] += (double)v[j] * (double)v[j];
      }
    }
    float4 vv = { v[0], v[1], v[2], v[3] };
    *(float4*)&out[(size_t)(row0 + (ty << 2) + i) * F + col0 + (tx << 2)] = vv;
  }
  if (STATS) {
#pragma unroll
    for (int j = 0; j < 4; j++) {
      sj[j] += __shfl_down(sj[j], 32);
      sj[j] += __shfl_down(sj[j], 16);
      qj[j] += __shfl_down(qj[j], 32);
      qj[j] += __shfl_down(qj[j], 16);
    }
    const int w = tid >> 6;
    if ((tid & 63) < 16) {
#pragma unroll
      for (int j = 0; j < 4; j++) {
        psumS[w][((tid & 15) << 2) + j] = sj[j];
        psqS[w][((tid & 15) << 2) + j] = qj[j];
      }
    }
    __syncthreads();
    if (tid < 64) {
      double ds = (psumS[0][tid] + psumS[1][tid]) + (psumS[2][tid] + psumS[3][tid]);
      double dq = (psqS[0][tid] + psqS[1][tid]) + (psqS[2][tid] + psqS[3][tid]);
      psum[(size_t)(col0 + tid) * 512 + blockIdx.y] = ds;
      psq[(size_t)(col0 + tid) * 512 + blockIdx.y] = dq;
    }
  }
}

// ---------------------------------------------------------------- async global->LDS
__device__ __forceinline__ void gld16(const void* gp, void* lp) {
  __builtin_amdgcn_global_load_lds(
      (__attribute__((address_space(1))) unsigned int*)gp,
      (__attribute__((address_space(3))) unsigned int*)lp,
      16, 0, 0);
}

#define MFMA16(a, b, c) __builtin_amdgcn_mfma_f32_16x16x32_bf16(a, b, c, 0, 0, 0)

// ---------------------------------------------------------------- quantize (bf16x3 MFMA + fp32 rescore)
// Software-pipelined (2-phase): double-buffered A/B tiles; the NEXT step's
// global_load_lds is issued BEFORE this step's ds_read+MFMA, so the implicit
// vmcnt(0) drain in __syncthreads() lands after ~500 cycles of compute.
// One barrier per k-step (was two + exposed L2 latency).
// Arithmetic identical to the passing round-3 kernel (same fragment values,
// same MFMA order, same top-2 / fp32-rescore sequence).
__global__ __launch_bounds__(256, 2)
void quantize_mfma(const float* __restrict__ Rf, u16* Rcvt,
                   const float* __restrict__ Ef, const u16* __restrict__ Ecvt,
                   const float* __restrict__ nEp, const float* __restrict__ rr,
                   float* __restrict__ ce, float* __restrict__ resn) {
  __shared__ __align__(16) u16 As[2][2][64][32];    // [buf][hi/lo][row][k]  16 KB
  __shared__ __align__(16) u16 Bs[2][2][128][32];   // [buf][hi/lo][code][k] 32 KB
  __shared__ float sD1[2][64], sD2[2][64];
  __shared__ int sI1[2][64], sI2[2][64];
  __shared__ int s_iA[64], s_iB[64];

  const int tid = threadIdx.x;
  const int row0 = blockIdx.x << 6;
  const int w = tid >> 6;          // wave 0..3
  const int lane = tid & 63;
  const int wr = w >> 1, wc = w & 1;
  const int l15 = lane & 15, l4 = lane >> 4;

  // per-lane rows: row0 + 32*wr + 16*i + 4*l4 + r   (s = i*4 + r)
  float rrv[8];
#pragma unroll
  for (int s = 0; s < 8; s++)
    rrv[s] = rr[row0 + 32 * wr + 16 * (s >> 2) + 4 * l4 + (s & 3)];

  float bd1[8], bd2[8];
  int bi1[8], bi2[8];
#pragma unroll
  for (int s = 0; s < 8; s++) { bd1[s] = 3.0e38f; bd2[s] = 3.0e38f; bi1[s] = 0; bi2[s] = 1; }

  // staging lane geometry: LDS dest linear (base + lane*16B); global source
  // k-chunk pre-swizzled so reads with the same XOR land conflict-free.
  const int str = lane >> 2;                                   // row within 16-row stripe
  const int sdst = (lane & 3) << 3;                            // linear LDS chunk (u16)
  const int ssrc = (((lane & 3) ^ ((lane >> 3) & 3)) << 3);    // swizzled source chunk (u16)
  const int krd = ((l15 >> 1) & 3) << 3;                       // read-side XOR key (u16)

  const u16* gAbase = Rcvt + (size_t)(row0 + 16 * w + str) * 512 + ssrc;
  const u16* gB0 = Ecvt + (size_t)(32 * w + str) * 512 + ssrc;        // q=0 row base
  const u16* gB1 = Ecvt + (size_t)(32 * w + 16 + str) * 512 + ssrc;   // q=1 row base
  const int rb0 = 32 * w + str, rb1 = 32 * w + 16 + str;

  // STAGE(buf, t): t in [0,128): n0 = (t>>3)*128 codes, k0 = (t&7)*32
#define STAGE(b, t)                                                         \
  {                                                                         \
    const int n0_ = ((t) >> 3) << 7, k0_ = ((t) & 7) << 5;                  \
    const u16* gA_ = gAbase + k0_;                                          \
    gld16(gA_,       &As[b][0][16 * w + str][sdst]);                        \
    gld16(gA_ + 256, &As[b][1][16 * w + str][sdst]);                        \
    const u16* g0_ = gB0 + (size_t)n0_ * 512 + k0_;                         \
    const u16* g1_ = gB1 + (size_t)n0_ * 512 + k0_;                         \
    gld16(g0_,       &Bs[b][0][rb0][sdst]);                                 \
    gld16(g0_ + 256, &Bs[b][1][rb0][sdst]);                                 \
    gld16(g1_,       &Bs[b][0][rb1][sdst]);                                 \
    gld16(g1_ + 256, &Bs[b][1][rb1][sdst]);                                 \
  }

  STAGE(0, 0);
  __syncthreads();   // prologue drain

  f32x4 acc[2][4] = {};
  float nn4[4];
#pragma unroll 2
  for (int t = 0; t < 128; t++) {
    const int b = t & 1;
    if ((t & 7) == 0) {   // preload nE for this n0-group (used 8 steps later)
      const int n0 = (t >> 3) << 7;
#pragma unroll
      for (int j = 0; j < 4; j++) nn4[j] = nEp[n0 + 64 * wc + 16 * j + l15];
    }
    if (t + 1 < 128) STAGE(b ^ 1, t + 1);   // issue next-step loads EARLY

    short8 ah[2], al[2], bh[4], bl[4];
#pragma unroll
    for (int i = 0; i < 2; i++) {
      const int ro = 32 * wr + 16 * i + l15;
      ah[i] = *(const short8*)&As[b][0][ro][(l4 << 3) ^ krd];
      al[i] = *(const short8*)&As[b][1][ro][(l4 << 3) ^ krd];
    }
#pragma unroll
    for (int j = 0; j < 4; j++) {
      const int ro = 64 * wc + 16 * j + l15;
      bh[j] = *(const short8*)&Bs[b][0][ro][(l4 << 3) ^ krd];
      bl[j] = *(const short8*)&Bs[b][1][ro][(l4 << 3) ^ krd];
    }
#pragma unroll
    for (int i = 0; i < 2; i++)
#pragma unroll
      for (int j = 0; j < 4; j++) {
        acc[i][j] = MFMA16(ah[i], bh[j], acc[i][j]);
        acc[i][j] = MFMA16(ah[i], bl[j], acc[i][j]);
        acc[i][j] = MFMA16(al[i], bh[j], acc[i][j]);
      }

    if ((t & 7) == 7) {
      // top-2 update: cols ascend with j and n0 -> strict < keeps first min
      const int n0 = (t >> 3) << 7;
#pragma unroll
      for (int j = 0; j < 4; j++) {
        const int col = n0 + 64 * wc + 16 * j + l15;
        const float nn = nn4[j];
#pragma unroll
        for (int i = 0; i < 2; i++)
#pragma unroll
          for (int r = 0; r < 4; r++) {
            const int s = i * 4 + r;
            float tt = rrv[s] - 2.0f * acc[i][j][r];
            float d = tt + nn;
            if (d < bd2[s]) {
              if (d < bd1[s]) {
                bd2[s] = bd1[s]; bi2[s] = bi1[s];
                bd1[s] = d; bi1[s] = col;
              } else {
                bd2[s] = d; bi2[s] = col;
              }
            }
          }
      }
#pragma unroll
      for (int i = 0; i < 2; i++)
#pragma unroll
        for (int j = 0; j < 4; j++) acc[i][j] = f32x4{0.f, 0.f, 0.f, 0.f};
    }
    __syncthreads();   // publishes t+1's tiles; frees buf b for t+2's stage
  }
#undef STAGE

  // merge top-2 pairs over the 16 lanes holding the same row (l15 dimension)
#pragma unroll
  for (int s = 0; s < 8; s++) {
    float d1 = bd1[s], d2 = bd2[s];
    int i1 = bi1[s], i2 = bi2[s];
#pragma unroll
    for (int off = 1; off <= 8; off <<= 1) {
      float e1 = __shfl_xor(d1, off, 16);
      float e2 = __shfl_xor(d2, off, 16);
      int j1 = __shfl_xor(i1, off, 16);
      int j2 = __shfl_xor(i2, off, 16);
      if (e1 < d1 || (e1 == d1 && j1 < i1)) {
        bool ps = (d1 < e2) || (d1 == e2 && i1 < j2);
        d2 = ps ? d1 : e2; i2 = ps ? i1 : j2;
        d1 = e1; i1 = j1;
      } else {
        bool ps = (e1 < d2) || (e1 == d2 && j1 < i2);
        if (ps) { d2 = e1; i2 = j1; }
      }
    }
    if (l15 == 0) {
      int lr = 32 * wr + 16 * (s >> 2) + 4 * l4 + (s & 3);
      sD1[wc][lr] = d1; sI1[wc][lr] = i1;
      sD2[wc][lr] = d2; sI2[wc][lr] = i2;
    }
  }
  __syncthreads();
  if (tid < 64) {
    float d1 = sD1[0][tid], d2 = sD2[0][tid];
    int i1 = sI1[0][tid], i2 = sI2[0][tid];
    float e1 = sD1[1][tid], e2 = sD2[1][tid];
    int j1 = sI1[1][tid], j2 = sI2[1][tid];
    int iA, iB;
    if (e1 < d1 || (e1 == d1 && j1 < i1)) {
      iA = j1;
      bool ps = (d1 < e2) || (d1 == e2 && i1 < j2);
      iB = ps ? i1 : j2;
    } else {
      iA = i1;
      bool ps = (e1 < d2) || (e1 == d2 && j1 < i2);
      iB = ps ? j1 : i2;
    }
    s_iA[tid] = iA; s_iB[tid] = iB;
  }
  __syncthreads();

  // fp32 rescore of the 2 candidates (4 threads per row), then gather +
  // residual + next-stage hi/lo conversion (in place, own rows only)
  const int orow = tid >> 2;
  const int q = tid & 3;
  const int gr = row0 + orow;
  const int iA = s_iA[orow], iB = s_iB[orow];
  const float* __restrict__ Rr = Rf + (size_t)gr * 256;
  const float* __restrict__ EA = Ef + (size_t)iA * 256;
  const float* __restrict__ EB = Ef + (size_t)iB * 256;
  float pa[4] = {0.f, 0.f, 0.f, 0.f}, pb[4] = {0.f, 0.f, 0.f, 0.f};
  const int c0 = q << 6;
  for (int t = 0; t < 16; t++) {
    float4 rv = *(const float4*)&Rr[c0 + 4 * t];
    float4 ea = *(const float4*)&EA[c0 + 4 * t];
    float4 eb = *(const float4*)&EB[c0 + 4 * t];
    pa[0] = fmaf(rv.x, ea.x, pa[0]); pa[1] = fmaf(rv.y, ea.y, pa[1]);
    pa[2] = fmaf(rv.z, ea.z, pa[2]); pa[3] = fmaf(rv.w, ea.w, pa[3]);
    pb[0] = fmaf(rv.x, eb.x, pb[0]); pb[1] = fmaf(rv.y, eb.y, pb[1]);
    pb[2] = fmaf(rv.z, eb.z, pb[2]); pb[3] = fmaf(rv.w, eb.w, pb[3]);
  }
  float sA = (pa[0] + pa[1]) + (pa[2] + pa[3]);
  float sB = (pb[0] + pb[1]) + (pb[2] + pb[3]);
  sA += __shfl_xor(sA, 1, 4); sA += __shfl_xor(sA, 2, 4);
  sB += __shfl_xor(sB, 1, 4); sB += __shfl_xor(sB, 2, 4);
  const float rrow = rr[gr];
  float dA = (rrow - 2.0f * sA) + nEp[iA];
  float dB = (rrow - 2.0f * sB) + nEp[iB];
  const int idx = (dB < dA || (dB == dA && iB < iA)) ? iB : iA;

  const int oc0 = q << 6;
  const float* __restrict__ Er = Ef + (size_t)idx * 256;
  float* __restrict__ Cr = ce + (size_t)gr * 256;
  if (resn) {
    float* __restrict__ Nr = resn + (size_t)gr * 256;
    u16* Hr = Rcvt + (size_t)gr * 512;
    for (int c = oc0; c < oc0 + 64; c += 4) {
      float4 e = *(const float4*)&Er[c];
      float4 r = *(const float4*)&Rr[c];
      *(float4*)&Cr[c] = e;
      float4 dd = { r.x - e.x, r.y - e.y, r.z - e.z, r.w - e.w };
      *(float4*)&Nr[c] = dd;
      u16 h0 = f2bf(dd.x), h1 = f2bf(dd.y), h2 = f2bf(dd.z), h3 = f2bf(dd.w);
      us4 hv = { h0, h1, h2, h3 };
      us4 lv = { f2bf(dd.x - bf2f(h0)), f2bf(dd.y - bf2f(h1)),
                 f2bf(dd.z - bf2f(h2)), f2bf(dd.w - bf2f(h3)) };
      *(us4*)&Hr[c] = hv;
      *(us4*)&Hr[256 + c] = lv;
    }
  } else {
    for (int c = oc0; c < oc0 + 64; c += 4) {
      float4 e = *(const float4*)&Er[c];
      *(float4*)&Cr[c] = e;
    }
  }
}

// ---------------------------------------------------------------- launch
extern "C" void kernel_launch(void* const* d_in, const int* in_sizes, int n_in,
                              void* d_out, int out_size, void* d_ws, size_t ws_size,
                              hipStream_t stream) {
  (void)in_sizes; (void)n_in; (void)out_size; (void)ws_size;
  const float* x     = (const float*)d_in[0];
  const float* pos   = (const float*)d_in[1];
  const float* e_w0  = (const float*)d_in[2];
  const float* e_b0  = (const float*)d_in[3];
  const float* e_g0  = (const float*)d_in[4];
  const float* e_bt0 = (const float*)d_in[5];
  const float* e_w1  = (const float*)d_in[6];
  const float* e_b1  = (const float*)d_in[7];
  const float* e_g1  = (const float*)d_in[8];
  const float* e_bt1 = (const float*)d_in[9];
  const float* e_w2  = (const float*)d_in[10];
  const float* e_b2  = (const float*)d_in[11];
  const float* cb    = (const float*)d_in[12];
  const float* d_w0  = (const float*)d_in[13];
  const float* d_b0  = (const float*)d_in[14];
  const float* d_g0  = (const float*)d_in[15];
  const float* d_bt0 = (const float*)d_in[16];
  const float* d_w1  = (const float*)d_in[17];
  const float* d_b1  = (const float*)d_in[18];
  const float* d_g1  = (const float*)d_in[19];
  const float* d_bt1 = (const float*)d_in[20];
  const float* d_w2  = (const float*)d_in[21];
  const float* d_b2  = (const float*)d_in[22];

  // ---------------- workspace layout (float offsets) ----------
  float* ws = (float*)d_ws;
  float* mask   = ws + 64;                         // 64
  float* aff    = ws + 128;                        // 1536
  float* nE     = ws + 1664;                       // 8192
  double* psum  = (double*)(ws + 16384);           // 131072 dbl
  double* psq   = (double*)(ws + 278528);          // 131072 dbl
  float* g1     = ws + 540672;                     // dec h1' [N,256]
  float* g0     = g1 + (size_t)N_ROWS * 256;       // dec h0' [N,128]
  float* rr     = g0 + (size_t)N_ROWS * 128;       // N

  float* e0a = aff + 0;    float* e0c = aff + 128;
  float* e1a = aff + 256;  float* e1c = aff + 512;
  float* d0a = aff + 768;  float* d0c = aff + 1024;
  float* d1a = aff + 1280; float* d1c = aff + 1408;

  // ---------------- output layout ----------------
  float* outp = (float*)d_out;
  float* xhat = outp;
  float* res0 = outp + (size_t)N_ROWS * 64;
  float* res1 = res0 + (size_t)N_ROWS * 256;
  float* res2 = res1 + (size_t)N_ROWS * 256;
  float* res3 = res2 + (size_t)N_ROWS * 256;
  float* ce0  = res0 + (size_t)4 * N_ROWS * 256;
  float* ce1  = ce0 + (size_t)N_ROWS * 256;
  float* ce2  = ce1 + (size_t)N_ROWS * 256;
  float* ce3  = ce2 + (size_t)N_ROWS * 256;

  // scratch overlays into not-yet-written output regions (lifetime-checked):
  float* h0 = ce2;   // enc h0 [N,128]; ce2 written at quantize stage 2
  float* h1 = ce3;   // enc h1 [N,256]; ce3 written at quantize stage 3
  // bf16 hi/lo overlays:
  //  - Ecvt (8192x512 u16 = 8.0 MB) sits in xhat (8.0 MB), free until final gemm
  //  - Rcvt (32768x512 u16 = 32 MB) sits in ce3 (exact size); each quantize block
  //    reads only its own 64 rows and rewrites them after its last read; stage 3
  //    overwrites the region with ce3 fp32 in its epilogue.
  u16* Ecvt = (u16*)xhat;
  u16* Rcvt = (u16*)ce3;

  mask_kernel<<<1, 64, 0, stream>>>(mask);
  norme_kernel<<<32, 256, 0, stream>>>(cb, nE);
  cvt_kernel<<<1024, 256, 0, stream>>>(cb, Ecvt);           // 8192 codebook rows

  // encoder
  gemm64<0, 1><<<dim3(2, 512), 256, 0, stream>>>(x, e_w0, e_b0, mask, pos, nullptr,
                                                 h0, psum, psq, 64, 128);
  bnprep_kernel<<<1, 256, 0, stream>>>(psum, psq, e_g0, e_bt0, e0a, e0c, 128);
  gemm64<1, 1><<<dim3(4, 512), 256, 0, stream>>>(h0, e_w1, e_b1, e0a, e0c, nullptr,
                                                 h1, psum, psq, 128, 256);
  bnprep_kernel<<<1, 256, 0, stream>>>(psum, psq, e_g1, e_bt1, e1a, e1c, 256);
  gemm64<1, 0><<<dim3(4, 512), 256, 0, stream>>>(h1, e_w2, e_b2, e1a, e1c, nullptr,
                                                 res0, nullptr, nullptr, 256, 256);

  // residual VQ (bf16x3 MFMA distance GEMM + fp32 rescore)
  cvt_kernel<<<4096, 256, 0, stream>>>(res0, Rcvt);         // 32768 rows
  rownorm_kernel<<<512, 256, 0, stream>>>(res0, rr);
  quantize_mfma<<<512, 256, 0, stream>>>(res0, Rcvt,
                                         cb + (size_t)0 * 2048 * 256,
                                         Ecvt + (size_t)0 * 2048 * 512,
                                         nE + 0, rr, ce0, res1);
  rownorm_kernel<<<512, 256, 0, stream>>>(res1, rr);
  quantize_mfma<<<512, 256, 0, stream>>>(res1, Rcvt,
                                         cb + (size_t)1 * 2048 * 256,
                                         Ecvt + (size_t)1 * 2048 * 512,
                                         nE + 2048, rr, ce1, res2);
  rownorm_kernel<<<512, 256, 0, stream>>>(res2, rr);
  quantize_mfma<<<512, 256, 0, stream>>>(res2, Rcvt,
                                         cb + (size_t)2 * 2048 * 256,
                                         Ecvt + (size_t)2 * 2048 * 512,
                                         nE + 4096, rr, ce2, res3);
  rownorm_kernel<<<512, 256, 0, stream>>>(res3, rr);
  quantize_mfma<<<512, 256, 0, stream>>>(res3, Rcvt,
                                         cb + (size_t)3 * 2048 * 256,
                                         Ecvt + (size_t)3 * 2048 * 512,
                                         nE + 6144, rr, ce3, nullptr);

  // decoder (L0 fuses zq = ((ce0+ce1)+ce2)+ce3 in the A prologue)
  gemm64<3, 1><<<dim3(4, 512), 256, 0, stream>>>(ce0, d_w0, d_b0, ce1, ce2, ce3,
                                                 g1, psum, psq, 256, 256);
  bnprep_kernel<<<1, 256, 0, stream>>>(psum, psq, d_g0, d_bt0, d0a, d0c, 256);
  gemm64<1, 1><<<dim3(2, 512), 256, 0, stream>>>(g1, d_w1, d_b1, d0a, d0c, nullptr,
                                                 g0, psum, psq, 256, 128);
  bnprep_kernel<<<1, 256, 0, stream>>>(psum, psq, d_g1, d_bt1, d1a, d1c, 128);
  gemm64<1, 0><<<dim3(1, 512), 256, 0, stream>>>(g0, d_w2, d_b2, d1a, d1c, nullptr,
                                                 xhat, nullptr, nullptr, 128, 64);
}